// Round 12
// baseline (148.698 us; speedup 1.0000x reference)
//
#include <hip/hip_runtime.h>
#include <stdint.h>

// DN4 image-to-class via bf16 MFMA, round 12: VGPR fix + component ablation.
// Real pipeline = round 11 with __launch_bounds__(512,4) on dn4_mfma.
// Ablation dispatches (write ws scratch only, REP=2):
//   abl<0> full main loop      abl<1> no top-3 lattice      abl<2> no global_load_lds

#define C_CLS 5
#define SHOTS 5
#define DIM 64
#define HW 256
#define NQ 75
#define K1 3
#define K2 64
#define M_TOT 1280
#define MQ 4
#define NIT 5                 // 64-row tiles per quarter
#define QG 2                  // 16-query groups per wave

using bf16x8 = __attribute__((ext_vector_type(8))) short;
using u32x4  = __attribute__((ext_vector_type(4))) unsigned int;
using f32x4  = __attribute__((ext_vector_type(4))) float;

typedef __attribute__((address_space(1))) const unsigned int GU32;
typedef __attribute__((address_space(3))) unsigned int LU32;

__device__ __forceinline__ void gload16(const void* g, void* l) {
    __builtin_amdgcn_global_load_lds((GU32*)g, (LU32*)l, 16, 0, 0);
}

__device__ inline unsigned short f2bf(float x) {
    uint32_t u = __float_as_uint(x);
    u += 0x7FFF + ((u >> 16) & 1);          // RNE
    return (unsigned short)(u >> 16);
}

__device__ __forceinline__ void ins3(float v, float& t0, float& t1, float& t2) {
    t2 = __builtin_amdgcn_fmed3f(v, t1, t2);
    t1 = __builtin_amdgcn_fmed3f(v, t0, t1);
    t0 = fmaxf(t0, v);
}

// ---------------- prep (unchanged, verified) ----------------
__global__ __launch_bounds__(256)
void prep(const float* __restrict__ support, const float* __restrict__ query,
          unsigned short* __restrict__ Sn, unsigned short* __restrict__ Qn) {
    const int tid  = threadIdx.x;
    const int wv   = tid >> 6, lane = tid & 63;
    const int dg   = lane >> 4, dl = lane & 15;
    const int bid  = blockIdx.x;
    const float* src;
    unsigned short* dstblk;
    if (bid < NQ * 4) {
        const int b    = bid >> 2;
        const int desc = (bid & 3) * 64 + wv * 16 + dl;
        src    = query + (size_t)b * DIM * HW + desc;
        dstblk = Qn + (size_t)b * 16384 + (size_t)((bid & 3) * 4 + wv) * 1024;
    } else {
        const int sb   = bid - NQ * 4;
        const int cs   = sb >> 2;
        const int desc = (sb & 3) * 64 + wv * 16 + dl;
        const int c = cs / SHOTS, s = cs % SHOTS;
        src    = support + (size_t)cs * DIM * HW + desc;
        dstblk = Sn + (size_t)c * 81920 + (size_t)(s * 16 + (sb & 3) * 4 + wv) * 1024;
    }
    float v[16];
    float nrm = 0.f;
#pragma unroll
    for (int i = 0; i < 16; ++i) {
        const float x = src[(dg * 16 + i) * HW];
        v[i] = x; nrm = fmaf(x, x, nrm);
    }
    nrm += __shfl_xor(nrm, 16, 64);
    nrm += __shfl_xor(nrm, 32, 64);
    const float inv = rsqrtf(nrm);
    uint32_t p[8];
#pragma unroll
    for (int j = 0; j < 8; ++j)
        p[j] = (uint32_t)f2bf(v[2 * j] * inv) | ((uint32_t)f2bf(v[2 * j + 1] * inv) << 16);
    const int ck = dg >> 1;
#pragma unroll
    for (int q = 0; q < 2; ++q) {
        const int kg = (dg & 1) * 2 + q;
        uint4 wq = {p[q * 4 + 0], p[q * 4 + 1], p[q * 4 + 2], p[q * 4 + 3]};
        *(uint4*)(dstblk + ck * 512 + (kg * 16 + dl) * 8) = wq;
    }
}

// ---------------- real main kernel (r11 + launch_bounds(512,4)) ----------------
__global__ __launch_bounds__(512, 4)
void dn4_mfma(const unsigned short* __restrict__ Sn,
              const unsigned short* __restrict__ Qn,
              unsigned short* __restrict__ partial) {
    __shared__ unsigned short sB[2][4 * 1024];

    const int tid  = threadIdx.x;
    const int lane = tid & 63, w = tid >> 6;
    const int c15  = lane & 15, kg = lane >> 4;
    const int bid  = blockIdx.x;
    const int b    = bid % NQ;
    const int cq   = bid / NQ;
    const int c    = cq >> 2, qt = cq & 3;

    bf16x8 aq[QG][2];
    const unsigned short* qf = Qn + (size_t)b * 16384 + (size_t)(w * QG) * 1024;
#pragma unroll
    for (int g = 0; g < QG; ++g)
#pragma unroll
        for (int ck = 0; ck < 2; ++ck)
            aq[g][ck] = __builtin_bit_cast(bf16x8,
                *(const u32x4*)(qf + g * 1024 + ck * 512 + lane * 8));

    float t0[QG][4], t1[QG][4], t2[QG][4];
#pragma unroll
    for (int g = 0; g < QG; ++g)
#pragma unroll
        for (int r = 0; r < 4; ++r) { t0[g][r] = -2.f; t1[g][r] = -2.f; t2[g][r] = -2.f; }

    const f32x4 Z = {0.f, 0.f, 0.f, 0.f};
    const char* tb0 = (const char*)Sn + (size_t)c * 163840 + (size_t)qt * 40960;

    gload16(tb0 + tid * 16, (char*)sB[0] + w * 1024);
    __syncthreads();

    int cur = 0;
    for (int it = 0; it < NIT; ++it) {
        if (it < NIT - 1) {
            const char* tb = tb0 + (size_t)(it + 1) * 8192;
            gload16(tb + tid * 16, (char*)sB[cur ^ 1] + w * 1024);
        }
#pragma unroll
        for (int ns = 0; ns < 4; ++ns) {
            const unsigned short* rp = &sB[cur][ns * 1024 + lane * 8];
            const bf16x8 b0 = __builtin_bit_cast(bf16x8, *(const u32x4*)rp);
            const bf16x8 b1 = __builtin_bit_cast(bf16x8, *(const u32x4*)(rp + 512));
#pragma unroll
            for (int g = 0; g < QG; ++g) {
                f32x4 acc = __builtin_amdgcn_mfma_f32_16x16x32_bf16(aq[g][0], b0, Z, 0, 0, 0);
                acc = __builtin_amdgcn_mfma_f32_16x16x32_bf16(aq[g][1], b1, acc, 0, 0, 0);
#pragma unroll
                for (int r = 0; r < 4; ++r)
                    ins3(acc[r], t0[g][r], t1[g][r], t2[g][r]);
            }
        }
        __syncthreads();
        cur ^= 1;
    }

#pragma unroll
    for (int g = 0; g < QG; ++g)
#pragma unroll
        for (int r = 0; r < 4; ++r)
#pragma unroll
            for (int off = 1; off < 16; off <<= 1) {
                const float o0 = __shfl_xor(t0[g][r], off, 64);
                const float o1 = __shfl_xor(t1[g][r], off, 64);
                const float o2 = __shfl_xor(t2[g][r], off, 64);
                const float x = fmaxf(t0[g][r], o2);
                const float y = fmaxf(t1[g][r], o1);
                const float z = fmaxf(t2[g][r], o0);
                t0[g][r] = fmaxf(fmaxf(x, y), z);
                t1[g][r] = __builtin_amdgcn_fmed3f(x, y, z);
                t2[g][r] = fminf(fminf(x, y), z);
            }

    if (c15 == 0) {
        unsigned short* pbase =
            partial + (((size_t)(c * NQ + b) * MQ + qt) * K1) * HW;
#pragma unroll
        for (int g = 0; g < QG; ++g)
#pragma unroll
            for (int r = 0; r < 4; ++r) {
                const int qloc = (w * QG + g) * 16 + kg * 4 + r;
                pbase[qloc]          = f2bf(t0[g][r]);
                pbase[HW + qloc]     = f2bf(t1[g][r]);
                pbase[2 * HW + qloc] = f2bf(t2[g][r]);
            }
    }
}

// ---------------- ablation: MODE 0=full, 1=no-lattice, 2=no-gload ----------------
template<int MODE>
__global__ __launch_bounds__(512, 4)
void abl(const unsigned short* __restrict__ Sn,
         const unsigned short* __restrict__ Qn,
         float* __restrict__ dbg) {
    __shared__ unsigned short sB[2][4 * 1024];

    const int tid  = threadIdx.x;
    const int lane = tid & 63, w = tid >> 6;
    const int bid  = blockIdx.x;
    const int b    = bid % NQ;
    const int cq   = bid / NQ;
    const int c    = cq >> 2, qt = cq & 3;

    bf16x8 aq[QG][2];
    const unsigned short* qf = Qn + (size_t)b * 16384 + (size_t)(w * QG) * 1024;
#pragma unroll
    for (int g = 0; g < QG; ++g)
#pragma unroll
        for (int ck = 0; ck < 2; ++ck)
            aq[g][ck] = __builtin_bit_cast(bf16x8,
                *(const u32x4*)(qf + g * 1024 + ck * 512 + lane * 8));

    float t0[QG][4], t1[QG][4], t2[QG][4];
#pragma unroll
    for (int g = 0; g < QG; ++g)
#pragma unroll
        for (int r = 0; r < 4; ++r) { t0[g][r] = -2.f; t1[g][r] = -2.f; t2[g][r] = -2.f; }

    const f32x4 Z = {0.f, 0.f, 0.f, 0.f};
    const char* tb0 = (const char*)Sn + (size_t)c * 163840 + (size_t)qt * 40960;

    for (int rep = 0; rep < 2; ++rep) {          // REP=2: keep dispatch >50us
        if (MODE != 2) gload16(tb0 + tid * 16, (char*)sB[0] + w * 1024);
        __syncthreads();
        int cur = 0;
        for (int it = 0; it < NIT; ++it) {
            if (MODE != 2 && it < NIT - 1) {
                const char* tb = tb0 + (size_t)(it + 1) * 8192;
                gload16(tb + tid * 16, (char*)sB[cur ^ 1] + w * 1024);
            }
#pragma unroll
            for (int ns = 0; ns < 4; ++ns) {
                const unsigned short* rp = &sB[cur][ns * 1024 + lane * 8];
                const bf16x8 b0 = __builtin_bit_cast(bf16x8, *(const u32x4*)rp);
                const bf16x8 b1 = __builtin_bit_cast(bf16x8, *(const u32x4*)(rp + 512));
#pragma unroll
                for (int g = 0; g < QG; ++g) {
                    f32x4 acc = __builtin_amdgcn_mfma_f32_16x16x32_bf16(aq[g][0], b0, Z, 0, 0, 0);
                    acc = __builtin_amdgcn_mfma_f32_16x16x32_bf16(aq[g][1], b1, acc, 0, 0, 0);
                    if (MODE == 1) {
                        // keep MFMA result live without consuming VALU (rule #17)
                        asm volatile("" :: "v"(acc[0]), "v"(acc[1]), "v"(acc[2]), "v"(acc[3]));
                    } else {
#pragma unroll
                        for (int r = 0; r < 4; ++r)
                            ins3(acc[r], t0[g][r], t1[g][r], t2[g][r]);
                    }
                }
            }
            __syncthreads();
            cur ^= 1;
        }
    }

    float s = 0.f;
#pragma unroll
    for (int g = 0; g < QG; ++g)
#pragma unroll
        for (int r = 0; r < 4; ++r) s += t0[g][r] + t1[g][r] + t2[g][r];
    dbg[(size_t)bid * 512 + tid] = s;
}

// ---------------- topq (unchanged, verified) ----------------
__global__ __launch_bounds__(256)
void dn4_topq(const unsigned short* __restrict__ partial, float* __restrict__ out) {
    __shared__ float sbuf[HW];
    const int tid = threadIdx.x;
    const int bid = blockIdx.x;
    const int ki  = bid % K1;
    const int cb  = bid / K1;

    const unsigned short* p = partial + (size_t)cb * MQ * K1 * HW + tid;
    float t0 = -2.f, t1 = -2.f, t2 = -2.f;
#pragma unroll
    for (int h = 0; h < MQ; ++h)
#pragma unroll
        for (int r = 0; r < K1; ++r) {
            const float v = __uint_as_float((uint32_t)p[(h * K1 + r) * HW] << 16);
            ins3(v, t0, t1, t2);
        }
    float v = (ki == 0) ? t0 : (ki == 1) ? t1 : t2;

#pragma unroll
    for (int kk = 2; kk <= HW; kk <<= 1) {
#pragma unroll
        for (int j = kk >> 1; j > 0; j >>= 1) {
            const bool keep_max = (((tid & kk) == 0) == ((tid & j) == 0));
            float wv;
            if (j >= 64) {
                sbuf[tid] = v;
                __syncthreads();
                wv = sbuf[tid ^ j];
                __syncthreads();
            } else {
                wv = __shfl_xor(v, j, 64);
            }
            v = keep_max ? fmaxf(v, wv) : fminf(v, wv);
        }
    }
    if (tid < K2) out[(size_t)cb * K1 * K2 + (size_t)ki * K2 + tid] = v;
}

extern "C" void kernel_launch(void* const* d_in, const int* in_sizes, int n_in,
                              void* d_out, int out_size, void* d_ws, size_t ws_size,
                              hipStream_t stream) {
    const float* support = (const float*)d_in[0];
    const float* query   = (const float*)d_in[1];
    float* out = (float*)d_out;

    char* ws = (char*)d_ws;
    unsigned short* Sn      = (unsigned short*)ws;
    unsigned short* Qn      = (unsigned short*)(ws + 819200);
    unsigned short* partial = (unsigned short*)(ws + 819200 + 2457600);
    float* dbg              = (float*)(ws + 819200 + 2457600 + 2304000);  // 3 MB scratch

    // real pipeline
    prep    <<<dim3(400),              dim3(256), 0, stream>>>(support, query, Sn, Qn);
    dn4_mfma<<<dim3(C_CLS * MQ * NQ),  dim3(512), 0, stream>>>(Sn, Qn, partial);
    dn4_topq<<<dim3(C_CLS * NQ * K1),  dim3(256), 0, stream>>>(partial, out);

    // ablation probes (scratch only; deterministic; inflate total this round on purpose)
    abl<0><<<dim3(C_CLS * MQ * NQ), dim3(512), 0, stream>>>(Sn, Qn, dbg);
    abl<1><<<dim3(C_CLS * MQ * NQ), dim3(512), 0, stream>>>(Sn, Qn, dbg);
    abl<2><<<dim3(C_CLS * MQ * NQ), dim3(512), 0, stream>>>(Sn, Qn, dbg);
}

// Round 13
// 55.815 us; speedup vs baseline: 2.6641x; 2.6641x over previous
//
#include <hip/hip_runtime.h>
#include <stdint.h>

// DN4 image-to-class via bf16 MFMA, round 13: longer phases, more blocks, setprio.
// prep:     normalize descriptors into MFMA fragment order (verified r9-r12):
//           per 16-descriptor block, 1024 us: [ck][kg*16+row][8].
// dn4_mfma: grid 1875 = (c, M-fifth, b); 512 threads = 8 waves x 32 queries;
//           two 128-row tiles (16 KB) double-buffered in LDS via linear
//           global_load_lds; 8 ns-steps between barriers (4 barriers/block);
//           s_setprio(1) around compute; per-lane top-3; bitonic triple-merge.
// dn4_topq: merge 5 fifths x top-3, shfl-bitonic descending sort 256 -> 64.

#define C_CLS 5
#define SHOTS 5
#define DIM 64
#define HW 256
#define NQ 75
#define K1 3
#define K2 64
#define M_TOT 1280
#define MQ 5                  // M fifths (grid-level split), 256 rows each
#define NTILE 2               // 128-row (16 KB) tiles per fifth
#define QG 2                  // 16-query groups per wave (32 q/wave)

using bf16x8 = __attribute__((ext_vector_type(8))) short;
using u32x4  = __attribute__((ext_vector_type(4))) unsigned int;
using f32x4  = __attribute__((ext_vector_type(4))) float;

typedef __attribute__((address_space(1))) const unsigned int GU32;
typedef __attribute__((address_space(3))) unsigned int LU32;

__device__ __forceinline__ void gload16(const void* g, void* l) {
    __builtin_amdgcn_global_load_lds((GU32*)g, (LU32*)l, 16, 0, 0);
}

__device__ inline unsigned short f2bf(float x) {
    uint32_t u = __float_as_uint(x);
    u += 0x7FFF + ((u >> 16) & 1);          // RNE
    return (unsigned short)(u >> 16);
}

__device__ __forceinline__ void ins3(float v, float& t0, float& t1, float& t2) {
    t2 = __builtin_amdgcn_fmed3f(v, t1, t2);
    t1 = __builtin_amdgcn_fmed3f(v, t0, t1);
    t0 = fmaxf(t0, v);
}

// ---------------- prep (unchanged, verified) ----------------
__global__ __launch_bounds__(256)
void prep(const float* __restrict__ support, const float* __restrict__ query,
          unsigned short* __restrict__ Sn, unsigned short* __restrict__ Qn) {
    const int tid  = threadIdx.x;
    const int wv   = tid >> 6, lane = tid & 63;
    const int dg   = lane >> 4, dl = lane & 15;
    const int bid  = blockIdx.x;
    const float* src;
    unsigned short* dstblk;
    if (bid < NQ * 4) {
        const int b    = bid >> 2;
        const int desc = (bid & 3) * 64 + wv * 16 + dl;
        src    = query + (size_t)b * DIM * HW + desc;
        dstblk = Qn + (size_t)b * 16384 + (size_t)((bid & 3) * 4 + wv) * 1024;
    } else {
        const int sb   = bid - NQ * 4;
        const int cs   = sb >> 2;
        const int desc = (sb & 3) * 64 + wv * 16 + dl;
        const int c = cs / SHOTS, s = cs % SHOTS;
        src    = support + (size_t)cs * DIM * HW + desc;
        dstblk = Sn + (size_t)c * 81920 + (size_t)(s * 16 + (sb & 3) * 4 + wv) * 1024;
    }
    float v[16];
    float nrm = 0.f;
#pragma unroll
    for (int i = 0; i < 16; ++i) {
        const float x = src[(dg * 16 + i) * HW];
        v[i] = x; nrm = fmaf(x, x, nrm);
    }
    nrm += __shfl_xor(nrm, 16, 64);
    nrm += __shfl_xor(nrm, 32, 64);
    const float inv = rsqrtf(nrm);
    uint32_t p[8];
#pragma unroll
    for (int j = 0; j < 8; ++j)
        p[j] = (uint32_t)f2bf(v[2 * j] * inv) | ((uint32_t)f2bf(v[2 * j + 1] * inv) << 16);
    const int ck = dg >> 1;
#pragma unroll
    for (int q = 0; q < 2; ++q) {
        const int kg = (dg & 1) * 2 + q;
        uint4 wq = {p[q * 4 + 0], p[q * 4 + 1], p[q * 4 + 2], p[q * 4 + 3]};
        *(uint4*)(dstblk + ck * 512 + (kg * 16 + dl) * 8) = wq;
    }
}

// grid 1875: bid = (c*MQ + qt)*NQ + b. 512 threads = 8 waves x 32 queries.
__global__ __launch_bounds__(512)
void dn4_mfma(const unsigned short* __restrict__ Sn,
              const unsigned short* __restrict__ Qn,
              unsigned short* __restrict__ partial) {
    __shared__ unsigned short sB[2][8 * 1024];      // 2 x 16 KB (8 fragment blocks)

    const int tid  = threadIdx.x;
    const int lane = tid & 63, w = tid >> 6;
    const int c15  = lane & 15, kg = lane >> 4;
    const int bid  = blockIdx.x;
    const int b    = bid % NQ;
    const int cq   = bid / NQ;                      // c*MQ + qt
    const int c    = cq / MQ, qt = cq % MQ;

    // ---- A fragments: contiguous 1KB wave streams (fragment layout) ----
    bf16x8 aq[QG][2];
    const unsigned short* qf = Qn + (size_t)b * 16384 + (size_t)(w * QG) * 1024;
#pragma unroll
    for (int g = 0; g < QG; ++g)
#pragma unroll
        for (int ck = 0; ck < 2; ++ck)
            aq[g][ck] = __builtin_bit_cast(bf16x8,
                *(const u32x4*)(qf + g * 1024 + ck * 512 + lane * 8));

    float t0[QG][4], t1[QG][4], t2[QG][4];
#pragma unroll
    for (int g = 0; g < QG; ++g)
#pragma unroll
        for (int r = 0; r < 4; ++r) { t0[g][r] = -2.f; t1[g][r] = -2.f; t2[g][r] = -2.f; }

    const f32x4 Z = {0.f, 0.f, 0.f, 0.f};
    // this fifth's 16 fragment blocks (32768 B)
    const char* tb0 = (const char*)Sn + (size_t)c * 163840 + (size_t)qt * 32768;

    // ---- prologue: stage tile 0 (16 KB = 512 threads x 2 x 16 B, linear) ----
#pragma unroll
    for (int rep = 0; rep < 2; ++rep)
        gload16(tb0 + rep * 8192 + tid * 16, (char*)sB[0] + rep * 8192 + tid * 16);
    __syncthreads();

    int cur = 0;
    for (int it = 0; it < NTILE; ++it) {
        if (it < NTILE - 1) {                       // issue next tile BEFORE compute
            const char* tb = tb0 + (size_t)(it + 1) * 16384;
#pragma unroll
            for (int rep = 0; rep < 2; ++rep)
                gload16(tb + rep * 8192 + tid * 16,
                        (char*)sB[cur ^ 1] + rep * 8192 + tid * 16);
        }
        __builtin_amdgcn_s_setprio(1);
#pragma unroll
        for (int ns = 0; ns < 8; ++ns) {            // 8 fragment blocks of 16 rows
            const unsigned short* rp = &sB[cur][ns * 1024 + lane * 8];
            const bf16x8 b0 = __builtin_bit_cast(bf16x8, *(const u32x4*)rp);
            const bf16x8 b1 = __builtin_bit_cast(bf16x8, *(const u32x4*)(rp + 512));
#pragma unroll
            for (int g = 0; g < QG; ++g) {
                f32x4 acc = __builtin_amdgcn_mfma_f32_16x16x32_bf16(aq[g][0], b0, Z, 0, 0, 0);
                acc = __builtin_amdgcn_mfma_f32_16x16x32_bf16(aq[g][1], b1, acc, 0, 0, 0);
#pragma unroll
                for (int r = 0; r < 4; ++r)
                    ins3(acc[r], t0[g][r], t1[g][r], t2[g][r]);
            }
        }
        __builtin_amdgcn_s_setprio(0);
        __syncthreads();                            // drains staging vmcnt too
        cur ^= 1;
    }

    // ---- merge across the 16 support-column lanes: bitonic triple-merge ----
#pragma unroll
    for (int g = 0; g < QG; ++g)
#pragma unroll
        for (int r = 0; r < 4; ++r)
#pragma unroll
            for (int off = 1; off < 16; off <<= 1) {
                const float o0 = __shfl_xor(t0[g][r], off, 64);
                const float o1 = __shfl_xor(t1[g][r], off, 64);
                const float o2 = __shfl_xor(t2[g][r], off, 64);
                const float x = fmaxf(t0[g][r], o2);
                const float y = fmaxf(t1[g][r], o1);
                const float z = fmaxf(t2[g][r], o0);
                t0[g][r] = fmaxf(fmaxf(x, y), z);
                t1[g][r] = __builtin_amdgcn_fmed3f(x, y, z);
                t2[g][r] = fminf(fminf(x, y), z);
            }

    if (c15 == 0) {
        unsigned short* pbase =
            partial + (((size_t)(c * NQ + b) * MQ + qt) * K1) * HW;
#pragma unroll
        for (int g = 0; g < QG; ++g)
#pragma unroll
            for (int r = 0; r < 4; ++r) {
                const int qloc = (w * QG + g) * 16 + kg * 4 + r;
                pbase[qloc]          = f2bf(t0[g][r]);
                pbase[HW + qloc]     = f2bf(t1[g][r]);
                pbase[2 * HW + qloc] = f2bf(t2[g][r]);
            }
    }
}

// grid 1125: (c*NQ+b)*3 + ki. Merge 5 fifths x top-3, shfl-bitonic sort, write 64.
__global__ __launch_bounds__(256)
void dn4_topq(const unsigned short* __restrict__ partial, float* __restrict__ out) {
    __shared__ float sbuf[HW];
    const int tid = threadIdx.x;
    const int bid = blockIdx.x;
    const int ki  = bid % K1;
    const int cb  = bid / K1;

    const unsigned short* p = partial + (size_t)cb * MQ * K1 * HW + tid;
    float t0 = -2.f, t1 = -2.f, t2 = -2.f;
#pragma unroll
    for (int h = 0; h < MQ; ++h)
#pragma unroll
        for (int r = 0; r < K1; ++r) {
            const float v = __uint_as_float((uint32_t)p[(h * K1 + r) * HW] << 16);
            ins3(v, t0, t1, t2);
        }
    float v = (ki == 0) ? t0 : (ki == 1) ? t1 : t2;

#pragma unroll
    for (int kk = 2; kk <= HW; kk <<= 1) {
#pragma unroll
        for (int j = kk >> 1; j > 0; j >>= 1) {
            const bool keep_max = (((tid & kk) == 0) == ((tid & j) == 0));
            float wv;
            if (j >= 64) {
                sbuf[tid] = v;
                __syncthreads();
                wv = sbuf[tid ^ j];
                __syncthreads();
            } else {
                wv = __shfl_xor(v, j, 64);
            }
            v = keep_max ? fmaxf(v, wv) : fminf(v, wv);
        }
    }
    if (tid < K2) out[(size_t)cb * K1 * K2 + (size_t)ki * K2 + tid] = v;
}

extern "C" void kernel_launch(void* const* d_in, const int* in_sizes, int n_in,
                              void* d_out, int out_size, void* d_ws, size_t ws_size,
                              hipStream_t stream) {
    const float* support = (const float*)d_in[0];
    const float* query   = (const float*)d_in[1];
    float* out = (float*)d_out;

    char* ws = (char*)d_ws;
    unsigned short* Sn      = (unsigned short*)ws;                      //   819,200 B
    unsigned short* Qn      = (unsigned short*)(ws + 819200);           // 2,457,600 B
    unsigned short* partial = (unsigned short*)(ws + 819200 + 2457600); // 2,880,000 B (6.16 MB)

    prep    <<<dim3(400),              dim3(256), 0, stream>>>(support, query, Sn, Qn);
    dn4_mfma<<<dim3(C_CLS * MQ * NQ),  dim3(512), 0, stream>>>(Sn, Qn, partial);
    dn4_topq<<<dim3(C_CLS * NQ * K1),  dim3(256), 0, stream>>>(partial, out);
}